// Round 6
// baseline (334.540 us; speedup 1.0000x reference)
//
#include <hip/hip_runtime.h>

// GRUModel: 2-layer GRU (H=64), B=4096, T=512, fp32 in/out — MFMA round 17.
//
// Model: window 1347 cyc = 659 VALU (trans floor 400) + 368 MFMA + 320 stall.
// Trans & MFMA counts are at algorithmic floor; R17 attacks the stall.
// Diagnosis: ONE __syncthreads per window phase-aligns both wave-groups, so
// the post-barrier serial chain (ds_read ~120cy -> MFMA chain -> trans chain
// -> ds_write -> drain) stalls both co-resident waves SIMULTANEOUSLY; their
// bubbles can't cover each other, and every window pays max(grp0, grp1).
// Fix: DECOUPLED PER-GROUP BARRIERS via LDS counters + cross-group
// thresholds, with h0 4-deep so grp0 drifts up to 3 windows ahead:
//   grp0@k: wait ctr0>=4k (own group) and ctr1>=4(k-3) (anti-dep: plane k&3
//           last read by grp1@k-3); write h0 plane k&3; release ctr0+=1/wave.
//   grp1@k: wait ctr0>=4k (h0(k-1) ready) and ctr1>=4(k-1) (own group);
//           read h0[(k-1)&3], h1[k&1]; write h1[(k+1)&1]; release ctr1.
// Release = s_waitcnt lgkmcnt(0) then lane-0 ds_add (REL); acquire = all-lane
// packed b64 spin (ACQ) + sched_barrier. Deadlock-free: g0@0,1 run free;
// g1@1 needs g0@0; g0@4 needs g1@1; ... Setprio(1) on MFMA clusters makes
// spinning waves yield issue to compute waves.
//
// Structure: 256 blocks x 512 threads; waves 0-3 layer 0, waves 4-7 layer 1
// (skewed 1 window); fp16 MFMA operands; h-state fp32 in registers; x folded
// into MFMA via fp16-packed LDS; gates in negated log2 domain (R13/R14);
// packed-f32 cell math (R15).
//
// Frag layouts (m89/m120-verified):
//   A: lane holds A[m=lane&15][k=(lane>>4)*8+j], j=0..7
//   B: lane holds B[k=(lane>>4)*8+j][n=lane&15]
//   C/D: lane holds D[m=(lane>>4)*4+reg][n=lane&15]

typedef _Float16 half8 __attribute__((ext_vector_type(8)));
typedef float    v4f   __attribute__((ext_vector_type(4)));
typedef float    v2f   __attribute__((ext_vector_type(2)));
typedef unsigned uint4v __attribute__((ext_vector_type(4)));

#define T_LEN 512
#define KS 72   // fp16 row stride of h planes (16B-aligned b128 reads)

#define L2E  1.4426950408889634f   // log2(e)
#define L2E2 2.8853900817779268f   // 2*log2(e)

static __device__ __forceinline__ v4f mfma16(half8 a, half8 b, v4f c) {
    return __builtin_amdgcn_mfma_f32_16x16x32_f16(a, b, c, 0, 0, 0);
}
static __device__ __forceinline__ half8 ld8(const _Float16* p) {
    return *(const half8*)p;
}
static __device__ __forceinline__ v2f exp2v(v2f x) {
    v2f r; r.x = __builtin_amdgcn_exp2f(x.x); r.y = __builtin_amdgcn_exp2f(x.y);
    return r;
}
static __device__ __forceinline__ v2f rcpv(v2f x) {
    v2f r; r.x = __builtin_amdgcn_rcpf(x.x); r.y = __builtin_amdgcn_rcpf(x.y);
    return r;
}
// merged GRU cell x2; inputs PRE-NEGATED & log2-scaled:
//   ar2 = -log2e*(i_r+h_r), az2 = -log2e*(i_z+h_z),
//   ni2 = -2log2e*i_n,      nh2 = -2log2e*h_n.
//   h' = [A(1-B) + h(1+B)] / [(1+A)(1+B)]; A=2^az2, B=2^wn, wn=ni2+r*nh2
// per pair: 10 trans (6 v_exp + 4 v_rcp) + 9 packed full-rate.
static __device__ __forceinline__ v2f gru_cell2(v2f ar2, v2f az2,
                                                v2f ni2, v2f nh2, v2f h) {
    const v2f C  = exp2v(ar2);                          // e^{-ar}
    const v2f r  = rcpv(C + 1.0f);                      // sigm(ar)
    const v2f wn = __builtin_elementwise_fma(r, nh2, ni2);
    const v2f A  = exp2v(az2);                          // e^{-az}
    const v2f Bv = exp2v(wn);                           // e^{-2(i_n+r*h_n)}
    const v2f aB = Bv + 1.0f;
    const v2f num = __builtin_elementwise_fma(h, aB, A * (1.0f - Bv));
    const v2f den = (A + 1.0f) * aB;
    return num * rcpv(den);
}

__global__ __launch_bounds__(512, 1)
void gru_mfma(const float* __restrict__ x,
              const float* __restrict__ w_ih0, const float* __restrict__ w_hh0,
              const float* __restrict__ b_ih0, const float* __restrict__ b_hh0,
              const float* __restrict__ w_ih1, const float* __restrict__ w_hh1,
              const float* __restrict__ b_ih1, const float* __restrict__ b_hh1,
              const float* __restrict__ fc_w,  const float* __restrict__ fc_b,
              float* __restrict__ out)
{
    // xh32[t][m]: fp16(x) in low 16 bits, high 16 = 0 — so a single
    // ds_read_b32 IS word0 of the x A-frag (elem0 = x, elem1 = 0).
    __shared__ __align__(16) unsigned xh32[T_LEN * 16];   // 32 KB
    __shared__ __align__(16) _Float16 h0f[4][16 * KS];    // h0 fp16, 4 planes
    __shared__ __align__(16) _Float16 h1f[2][16 * KS];    // h1 fp16, 2 planes
    __shared__ float red[64];
    __shared__ __align__(8) int ctr[2];   // windows completed x4 (per group)

    const int tid  = threadIdx.x;
    const int wv   = tid >> 6;
    const int grp  = wv >> 2;       // 0 = layer-0 group, 1 = layer-1 group
    const int w    = wv & 3;        // N-split within group
    const int lane = tid & 63;
    const int n    = lane & 15;
    const int q    = lane >> 4;
    const int u    = w * 16 + n;    // unit owned in gate phase

    // ---- stage this block's 16 x-rows into LDS as fp16-packed [t][m] ----
    const float* xg = x + (size_t)(blockIdx.x * 16) * T_LEN;
    for (int i = tid; i < 16 * T_LEN; i += 512) {
        const int row = i >> 9, t = i & 511;
        const float v = xg[row * T_LEN + t];
        xh32[t * 16 + row] =
            (unsigned)__builtin_bit_cast(unsigned short, (_Float16)v);
    }
    // zero the planes that are read before first write
    for (int i = tid; i < 16 * KS; i += 512) {
        h0f[3][i] = (_Float16)0;   // read by grp0@k=0 (plane (0-1)&3 = 3)
        h1f[1][i] = (_Float16)0;   // read by grp1@k=1 (plane 1&1 = 1)
    }
    if (tid == 0) { ctr[0] = 0; ctr[1] = 0; }

    // ---- loop-invariant weight B-fragments, pre-scaled into NEGATED log2
    // domain. grp0 uses c=0,1 (W_hh0, K=64); grp1 uses c=0..3
    // ([W_ih1 | W_hh1], K=128). gates r,z scaled by -log2e; n by -2log2e.
    half8 B[3][4];
    {
        const int rows[3] = {u, 64 + u, 128 + u};
        const float sc[3] = {-L2E, -L2E, -L2E2};
        const float* bc[4];
        if (grp == 0) {
            bc[0] = w_hh0;      bc[1] = w_hh0 + 32;
            bc[2] = w_hh0;      bc[3] = w_hh0 + 32;   // unused dups
        } else {
            bc[0] = w_ih1;      bc[1] = w_ih1 + 32;
            bc[2] = w_hh1;      bc[3] = w_hh1 + 32;
        }
        #pragma unroll
        for (int g = 0; g < 3; g++)
            #pragma unroll
            for (int c = 0; c < 4; c++) {
                const float* r0 = bc[c] + rows[g] * 64 + 8 * q;
                #pragma unroll
                for (int j = 0; j < 8; j++) B[g][c][j] = (_Float16)(r0[j] * sc[g]);
            }
    }

    // ---- x-chunk B-frags (grp0 only): Bx row k=0 = scaled w_ih0 gate row,
    // rows 1..31 = 0  ->  lane (q==0, j==0) holds w, all else 0.
    half8 BX[3];
    {
        const float sc3[3] = {-L2E, -L2E, -L2E2};
        #pragma unroll
        for (int g = 0; g < 3; g++) {
            uint4v z = {0u, 0u, 0u, 0u};
            if (grp == 0 && q == 0) {
                const _Float16 wv16 = (_Float16)(w_ih0[g * 64 + u] * sc3[g]);
                z.x = (unsigned)__builtin_bit_cast(unsigned short, wv16);
            }
            BX[g] = __builtin_bit_cast(half8, z);
        }
    }

    // per-lane gate bias constants for unit u (group-specific), -log2 scaled
    float brc, bzc, binc, bhnc;
    if (grp == 0) {
        brc = -(b_ih0[u] + b_hh0[u]) * L2E;
        bzc = -(b_ih0[64 + u] + b_hh0[64 + u]) * L2E;
        binc = -b_ih0[128 + u] * L2E2; bhnc = -b_hh0[128 + u] * L2E2;
    } else {
        brc = -(b_ih1[u] + b_hh1[u]) * L2E;
        bzc = -(b_ih1[64 + u] + b_hh1[64 + u]) * L2E;
        binc = -b_ih1[128 + u] * L2E2; bhnc = -b_hh1[128 + u] * L2E2;
    }

    // loop-invariant bias splats: C operand of the FIRST MFMA of each chain.
    const v4f biasR4  = {brc,  brc,  brc,  brc};
    const v4f biasZ4  = {bzc,  bzc,  bzc,  bzc};
    const v4f biasNi4 = {binc, binc, binc, binc};
    const v4f biasNh4 = {bhnc, bhnc, bhnc, bhnc};

    v2f hA = {0.f, 0.f}, hB = {0.f, 0.f};   // fp32 h[m=4q+{0,1,2,3}][u]

    __syncthreads();   // staging + ctr init visible to all

    const int abase = n * KS + 8 * q;       // A-frag base (fp16 elems)

    // ---- decoupled sync primitives ----
    auto wait2 = [&](int t0, int t1) __attribute__((always_inline)) {
        // spin until ctr[0] >= t0 && ctr[1] >= t1 (packed b64 acquire load)
        for (;;) {
            unsigned long long v = __hip_atomic_load(
                (const unsigned long long*)ctr, __ATOMIC_ACQUIRE,
                __HIP_MEMORY_SCOPE_WORKGROUP);
            const int c0 = (int)(unsigned)(v & 0xffffffffull);
            const int c1 = (int)(unsigned)(v >> 32);
            if (c0 >= t0 && c1 >= t1) break;
        }
        __builtin_amdgcn_sched_barrier(0);   // no hoisting past the acquire
    };
    auto release = [&](int g) __attribute__((always_inline)) {
        asm volatile("s_waitcnt lgkmcnt(0)" ::: "memory");  // writes retired
        if (lane == 0)
            __hip_atomic_fetch_add(&ctr[g], 1, __ATOMIC_RELEASE,
                                   __HIP_MEMORY_SCOPE_WORKGROUP);
    };

    // ---- window bodies (dynamic plane offsets; k is wave-uniform) ----
    auto grp0_step = [&](int k) __attribute__((always_inline)) {
        const _Float16* rp = &h0f[(k + 3) & 3][0];   // h0(k-1)
        _Float16*       wpbase = &h0f[k & 3][0];     // h0(k)
        const half8 a0 = ld8(rp + abase);
        const half8 a1 = ld8(rp + abase + 32);
        // x A-frag: k-slot 0 = x[m=n][t=k] (only q==0 lanes non-zero)
        const unsigned xw = xh32[k * 16 + n];
        uint4v ax32 = {0u, 0u, 0u, 0u};
        ax32.x = (q == 0) ? xw : 0u;
        const half8 ax = __builtin_bit_cast(half8, ax32);

        __builtin_amdgcn_s_setprio(1);
        v4f accR = mfma16(ax, BX[0], biasR4);
        v4f accZ = mfma16(ax, BX[1], biasZ4);
        v4f aNi  = mfma16(ax, BX[2], biasNi4);
        v4f accN = mfma16(a0, B[2][0], biasNh4);
        accR = mfma16(a0, B[0][0], accR);
        accZ = mfma16(a0, B[1][0], accZ);
        accN = mfma16(a1, B[2][1], accN);
        accR = mfma16(a1, B[0][1], accR);
        accZ = mfma16(a1, B[1][1], accZ);
        __builtin_amdgcn_s_setprio(0);

        const v2f h01 = gru_cell2((v2f){accR[0], accR[1]},
                                  (v2f){accZ[0], accZ[1]},
                                  (v2f){aNi[0],  aNi[1]},
                                  (v2f){accN[0], accN[1]}, hA);
        const v2f h23 = gru_cell2((v2f){accR[2], accR[3]},
                                  (v2f){accZ[2], accZ[3]},
                                  (v2f){aNi[2],  aNi[3]},
                                  (v2f){accN[2], accN[3]}, hB);
        hA = h01; hB = h23;
        _Float16* wp = wpbase + (4 * q) * KS + u;
        wp[0]      = (_Float16)h01.x;
        wp[KS]     = (_Float16)h01.y;
        wp[2 * KS] = (_Float16)h23.x;
        wp[3 * KS] = (_Float16)h23.y;
    };

    auto grp1_step = [&](int k) __attribute__((always_inline)) {
        // consumes h0(k-1) [plane (k-1)&3] and h1(k-2) [plane k&1];
        // writes h1(k-1) [plane (k+1)&1].
        const _Float16* r1 = &h1f[k & 1][0];
        const _Float16* r0 = &h0f[(k + 3) & 3][0];
        _Float16*       wpbase = &h1f[(k + 1) & 1][0];
        // own-layer frags first (written 1 window ago, ready)
        const half8 g10 = ld8(r1 + abase);
        const half8 g11 = ld8(r1 + abase + 32);
        const half8 g00 = ld8(r0 + abase);
        const half8 g01 = ld8(r0 + abase + 32);

        __builtin_amdgcn_s_setprio(1);
        v4f aR  = mfma16(g10, B[0][2], biasR4);
        v4f aZ  = mfma16(g10, B[1][2], biasZ4);
        v4f aNh = mfma16(g10, B[2][2], biasNh4);
        aR  = mfma16(g11, B[0][3], aR);
        aZ  = mfma16(g11, B[1][3], aZ);
        aNh = mfma16(g11, B[2][3], aNh);
        v4f aNi = mfma16(g00, B[2][0], biasNi4);
        aR  = mfma16(g00, B[0][0], aR);
        aZ  = mfma16(g00, B[1][0], aZ);
        aNi = mfma16(g01, B[2][1], aNi);
        aR  = mfma16(g01, B[0][1], aR);
        aZ  = mfma16(g01, B[1][1], aZ);
        __builtin_amdgcn_s_setprio(0);

        const v2f h01 = gru_cell2((v2f){aR[0], aR[1]},
                                  (v2f){aZ[0], aZ[1]},
                                  (v2f){aNi[0], aNi[1]},
                                  (v2f){aNh[0], aNh[1]}, hA);
        const v2f h23 = gru_cell2((v2f){aR[2], aR[3]},
                                  (v2f){aZ[2], aZ[3]},
                                  (v2f){aNi[2], aNi[3]},
                                  (v2f){aNh[2], aNh[3]}, hB);
        hA = h01; hB = h23;
        _Float16* wp = wpbase + (4 * q) * KS + u;
        wp[0]      = (_Float16)h01.x;
        wp[KS]     = (_Float16)h01.y;
        wp[2 * KS] = (_Float16)h23.x;
        wp[3 * KS] = (_Float16)h23.y;
    };

    // ---- decoupled window loops ----
    #pragma unroll 1
    for (int k = 0; k < T_LEN + 1; k++) {
        if (grp == 0) {
            if (k < T_LEN) {
                wait2(4 * k, (k >= 4) ? 4 * (k - 3) : 0);
                grp0_step(k);
                release(0);
            }
        } else {
            if (k > 0) {
                wait2(4 * k, 4 * (k - 1));
                grp1_step(k);
                release(1);
            }
        }
    }
    __syncthreads();

    // ======== FC epilogue: out[m] = sum_u fc_w[u] h1[m][u] + fc_b ========
    if (grp == 1) {
        const float fw = fc_w[u];
        const float hv[4] = {hA.x, hA.y, hB.x, hB.y};
        #pragma unroll
        for (int r = 0; r < 4; r++) {
            float v = fw * hv[r];
            v += __shfl_xor(v, 1, 64);
            v += __shfl_xor(v, 2, 64);
            v += __shfl_xor(v, 4, 64);
            v += __shfl_xor(v, 8, 64);   // sum over 16 n-lanes (q preserved)
            if (n == 0) red[(4 * q + r) * 4 + w] = v;
        }
    }
    __syncthreads();
    if (tid < 16) {
        const float s = red[tid * 4] + red[tid * 4 + 1] + red[tid * 4 + 2] + red[tid * 4 + 3];
        out[blockIdx.x * 16 + tid] = s + fc_b[0];
    }
}

extern "C" void kernel_launch(void* const* d_in, const int* in_sizes, int n_in,
                              void* d_out, int out_size, void* d_ws, size_t ws_size,
                              hipStream_t stream)
{
    const float* x     = (const float*)d_in[0];
    const float* w_ih0 = (const float*)d_in[1];
    const float* w_hh0 = (const float*)d_in[2];
    const float* b_ih0 = (const float*)d_in[3];
    const float* b_hh0 = (const float*)d_in[4];
    const float* w_ih1 = (const float*)d_in[5];
    const float* w_hh1 = (const float*)d_in[6];
    const float* b_ih1 = (const float*)d_in[7];
    const float* b_hh1 = (const float*)d_in[8];
    const float* fc_w  = (const float*)d_in[9];
    const float* fc_b  = (const float*)d_in[10];
    float* out = (float*)d_out;

    hipLaunchKernelGGL(gru_mfma, dim3(256), dim3(512), 0, stream,
                       x, w_ih0, w_hh0, b_ih0, b_hh0,
                       w_ih1, w_hh1, b_ih1, b_hh1, fc_w, fc_b, out);
}

// Round 7
// 321.448 us; speedup vs baseline: 1.0407x; 1.0407x over previous
//
#include <hip/hip_runtime.h>

// GRUModel: 2-layer GRU (H=64), B=4096, T=512, fp32 in/out — MFMA round 18.
//
// R17 lesson (measured): decoupled counter-barriers REGRESSED (288->305us) —
// the stall is NOT convoy skew; grp0/grp1 are rate-matched so pipeline depth
// never engages, and spin issue costs ~80 cyc/window. R18 = R16 revert
// (one s_barrier/window, literal parity, setprio) + chain-targeted trim:
//   - grp1 aR/aZ MFMA chains split 4-deep -> two independent 2-deep chains
//     (h1-side from bias, h0-side from zero) + v4f add. Crit path -35..60
//     cyc for +4 pk-adds/wave. aNh/aNi already depth-2.
//   - grp0 left as-is (chains depth<=3 with early operands; split costs more
//     issue than it saves).
//
// Model (R12-R16 calibrated): window 1347 = 659 VALU (trans floor 400) +
// 368 MFMA (HW floor) + 320 uncovered chain (ds_read ~120 + MFMA tree +
// trans chain). Issue floor ~980 -> ~210us absolute; this targets the chain.
//
// Structure: 256 blocks x 512 threads; waves 0-3 layer 0 @ window k,
// waves 4-7 layer 1 @ k-1; fp16 MFMA operands; one barrier/window; parity
// double-buffered h planes; h-state fp32 in registers; x folded into MFMA;
// negated log2-domain gates; packed-f32 cell math.
//
// Frag layouts (m89/m120-verified):
//   A: lane holds A[m=lane&15][k=(lane>>4)*8+j], j=0..7
//   B: lane holds B[k=(lane>>4)*8+j][n=lane&15]
//   C/D: lane holds D[m=(lane>>4)*4+reg][n=lane&15]

typedef _Float16 half8 __attribute__((ext_vector_type(8)));
typedef float    v4f   __attribute__((ext_vector_type(4)));
typedef float    v2f   __attribute__((ext_vector_type(2)));
typedef unsigned uint4v __attribute__((ext_vector_type(4)));

#define T_LEN 512
#define KS 72   // fp16 row stride of h planes (16B-aligned b128 reads)

#define L2E  1.4426950408889634f   // log2(e)
#define L2E2 2.8853900817779268f   // 2*log2(e)

static __device__ __forceinline__ v4f mfma16(half8 a, half8 b, v4f c) {
    return __builtin_amdgcn_mfma_f32_16x16x32_f16(a, b, c, 0, 0, 0);
}
static __device__ __forceinline__ half8 ld8(const _Float16* p) {
    return *(const half8*)p;
}
static __device__ __forceinline__ v2f exp2v(v2f x) {
    v2f r; r.x = __builtin_amdgcn_exp2f(x.x); r.y = __builtin_amdgcn_exp2f(x.y);
    return r;
}
static __device__ __forceinline__ v2f rcpv(v2f x) {
    v2f r; r.x = __builtin_amdgcn_rcpf(x.x); r.y = __builtin_amdgcn_rcpf(x.y);
    return r;
}
// merged GRU cell x2; inputs PRE-NEGATED & log2-scaled:
//   ar2 = -log2e*(i_r+h_r), az2 = -log2e*(i_z+h_z),
//   ni2 = -2log2e*i_n,      nh2 = -2log2e*h_n.
//   h' = [A(1-B) + h(1+B)] / [(1+A)(1+B)]; A=2^az2, B=2^wn, wn=ni2+r*nh2
// per pair: 10 trans (6 v_exp + 4 v_rcp) + 9 packed full-rate.
static __device__ __forceinline__ v2f gru_cell2(v2f ar2, v2f az2,
                                                v2f ni2, v2f nh2, v2f h) {
    const v2f C  = exp2v(ar2);                          // e^{-ar}
    const v2f r  = rcpv(C + 1.0f);                      // sigm(ar)
    const v2f wn = __builtin_elementwise_fma(r, nh2, ni2);
    const v2f A  = exp2v(az2);                          // e^{-az}
    const v2f Bv = exp2v(wn);                           // e^{-2(i_n+r*h_n)}
    const v2f aB = Bv + 1.0f;
    const v2f num = __builtin_elementwise_fma(h, aB, A * (1.0f - Bv));
    const v2f den = (A + 1.0f) * aB;
    return num * rcpv(den);
}

__global__ __launch_bounds__(512, 1)
void gru_mfma(const float* __restrict__ x,
              const float* __restrict__ w_ih0, const float* __restrict__ w_hh0,
              const float* __restrict__ b_ih0, const float* __restrict__ b_hh0,
              const float* __restrict__ w_ih1, const float* __restrict__ w_hh1,
              const float* __restrict__ b_ih1, const float* __restrict__ b_hh1,
              const float* __restrict__ fc_w,  const float* __restrict__ fc_b,
              float* __restrict__ out)
{
    // xh32[t][m]: fp16(x) in low 16 bits, high 16 = 0 — so a single
    // ds_read_b32 IS word0 of the x A-frag (elem0 = x, elem1 = 0).
    __shared__ __align__(16) unsigned xh32[T_LEN * 16];   // 32 KB
    __shared__ __align__(16) _Float16 h0f[2][16 * KS];    // h0 fp16, 2 parities
    __shared__ __align__(16) _Float16 h1f[2][16 * KS];    // h1 fp16, 2 parities
    __shared__ float red[64];

    const int tid  = threadIdx.x;
    const int wv   = tid >> 6;
    const int grp  = wv >> 2;       // 0 = layer-0 group, 1 = layer-1 group
    const int w    = wv & 3;        // N-split within group
    const int lane = tid & 63;
    const int n    = lane & 15;
    const int q    = lane >> 4;
    const int u    = w * 16 + n;    // unit owned in gate phase

    // ---- stage this block's 16 x-rows into LDS as fp16-packed [t][m] ----
    const float* xg = x + (size_t)(blockIdx.x * 16) * T_LEN;
    for (int i = tid; i < 16 * T_LEN; i += 512) {
        const int row = i >> 9, t = i & 511;
        const float v = xg[row * T_LEN + t];
        xh32[t * 16 + row] =
            (unsigned)__builtin_bit_cast(unsigned short, (_Float16)v);
    }
    // zero parity-1 buffers (read before first write)
    for (int i = tid; i < 16 * KS; i += 512) {
        h0f[1][i] = (_Float16)0;
        h1f[1][i] = (_Float16)0;
    }

    // ---- loop-invariant weight B-fragments, pre-scaled into NEGATED log2
    // domain. grp0 uses c=0,1 (W_hh0, K=64); grp1 uses c=0..3
    // ([W_ih1 | W_hh1], K=128). gates r,z scaled by -log2e; n by -2log2e.
    half8 B[3][4];
    {
        const int rows[3] = {u, 64 + u, 128 + u};
        const float sc[3] = {-L2E, -L2E, -L2E2};
        const float* bc[4];
        if (grp == 0) {
            bc[0] = w_hh0;      bc[1] = w_hh0 + 32;
            bc[2] = w_hh0;      bc[3] = w_hh0 + 32;   // unused dups
        } else {
            bc[0] = w_ih1;      bc[1] = w_ih1 + 32;
            bc[2] = w_hh1;      bc[3] = w_hh1 + 32;
        }
        #pragma unroll
        for (int g = 0; g < 3; g++)
            #pragma unroll
            for (int c = 0; c < 4; c++) {
                const float* r0 = bc[c] + rows[g] * 64 + 8 * q;
                #pragma unroll
                for (int j = 0; j < 8; j++) B[g][c][j] = (_Float16)(r0[j] * sc[g]);
            }
    }

    // ---- x-chunk B-frags (grp0 only): Bx row k=0 = scaled w_ih0 gate row,
    // rows 1..31 = 0  ->  lane (q==0, j==0) holds w, all else 0.
    half8 BX[3];
    {
        const float sc3[3] = {-L2E, -L2E, -L2E2};
        #pragma unroll
        for (int g = 0; g < 3; g++) {
            uint4v z = {0u, 0u, 0u, 0u};
            if (grp == 0 && q == 0) {
                const _Float16 wv16 = (_Float16)(w_ih0[g * 64 + u] * sc3[g]);
                z.x = (unsigned)__builtin_bit_cast(unsigned short, wv16);
            }
            BX[g] = __builtin_bit_cast(half8, z);
        }
    }

    // per-lane gate bias constants for unit u (group-specific), -log2 scaled
    float brc, bzc, binc, bhnc;
    if (grp == 0) {
        brc = -(b_ih0[u] + b_hh0[u]) * L2E;
        bzc = -(b_ih0[64 + u] + b_hh0[64 + u]) * L2E;
        binc = -b_ih0[128 + u] * L2E2; bhnc = -b_hh0[128 + u] * L2E2;
    } else {
        brc = -(b_ih1[u] + b_hh1[u]) * L2E;
        bzc = -(b_ih1[64 + u] + b_hh1[64 + u]) * L2E;
        binc = -b_ih1[128 + u] * L2E2; bhnc = -b_hh1[128 + u] * L2E2;
    }

    // loop-invariant bias splats: C operand of the FIRST MFMA of each chain.
    const v4f biasR4  = {brc,  brc,  brc,  brc};
    const v4f biasZ4  = {bzc,  bzc,  bzc,  bzc};
    const v4f biasNi4 = {binc, binc, binc, binc};
    const v4f biasNh4 = {bhnc, bhnc, bhnc, bhnc};
    const v4f zero4   = {0.f, 0.f, 0.f, 0.f};

    v2f hA = {0.f, 0.f}, hB = {0.f, 0.f};   // fp32 h[m=4q+{0,1,2,3}][u]

    __syncthreads();

    const int abase = n * KS + 8 * q;       // A-frag base (fp16 elems)

    // ---- window bodies; P = window parity, a LITERAL at every call site
    // so all parity-dependent LDS addresses fold to constants.
    auto grp0_step = [&](int k, int P) __attribute__((always_inline)) {
        const int pw = P, pr = P ^ 1;
        // A-frags of h0(k-1) — written @k-1 pre-barrier, visible now
        const half8 a0 = ld8(&h0f[pr][abase]);
        const half8 a1 = ld8(&h0f[pr][abase + 32]);
        // x A-frag: k-slot 0 = x[m=n][t=k] (only q==0 lanes non-zero)
        const unsigned xw = xh32[k * 16 + n];
        uint4v ax32 = {0u, 0u, 0u, 0u};
        ax32.x = (q == 0) ? xw : 0u;
        const half8 ax = __builtin_bit_cast(half8, ax32);

        __builtin_amdgcn_s_setprio(1);
        v4f accR = mfma16(ax, BX[0], biasR4);
        v4f accZ = mfma16(ax, BX[1], biasZ4);
        v4f aNi  = mfma16(ax, BX[2], biasNi4);
        v4f accN = mfma16(a0, B[2][0], biasNh4);
        accR = mfma16(a0, B[0][0], accR);
        accZ = mfma16(a0, B[1][0], accZ);
        accN = mfma16(a1, B[2][1], accN);
        accR = mfma16(a1, B[0][1], accR);
        accZ = mfma16(a1, B[1][1], accZ);
        __builtin_amdgcn_s_setprio(0);

        const v2f h01 = gru_cell2((v2f){accR[0], accR[1]},
                                  (v2f){accZ[0], accZ[1]},
                                  (v2f){aNi[0],  aNi[1]},
                                  (v2f){accN[0], accN[1]}, hA);
        const v2f h23 = gru_cell2((v2f){accR[2], accR[3]},
                                  (v2f){accZ[2], accZ[3]},
                                  (v2f){aNi[2],  aNi[3]},
                                  (v2f){accN[2], accN[3]}, hB);
        hA = h01; hB = h23;
        _Float16* wp = &h0f[pw][(4 * q) * KS + u];
        wp[0]      = (_Float16)h01.x;
        wp[KS]     = (_Float16)h01.y;
        wp[2 * KS] = (_Float16)h23.x;
        wp[3 * KS] = (_Float16)h23.y;
    };

    auto grp1_step = [&](int P) __attribute__((always_inline)) {
        // window k has parity P; consumes h0(t=k-1) (parity P^1) and
        // h1(t-1) (parity P), writes h1(t) at parity P^1.
        const int pw = P ^ 1, p1 = P;
        // own-layer frags first: written a full window ago, reads ready
        const half8 g10 = ld8(&h1f[p1][abase]);        // h1(t-1)
        const half8 g11 = ld8(&h1f[p1][abase + 32]);
        const half8 g00 = ld8(&h0f[pw][abase]);        // h0new(t)
        const half8 g01 = ld8(&h0f[pw][abase + 32]);

        __builtin_amdgcn_s_setprio(1);
        // TREE-SPLIT: aR/aZ as two independent depth-2 chains + add.
        // h1-side chains (data ready first):
        v4f aR1 = mfma16(g10, B[0][2], biasR4);
        v4f aZ1 = mfma16(g10, B[1][2], biasZ4);
        v4f aNh = mfma16(g10, B[2][2], biasNh4);
        aR1 = mfma16(g11, B[0][3], aR1);
        aZ1 = mfma16(g11, B[1][3], aZ1);
        aNh = mfma16(g11, B[2][3], aNh);
        // h0-side chains (independent, from zero):
        v4f aR0 = mfma16(g00, B[0][0], zero4);
        v4f aZ0 = mfma16(g00, B[1][0], zero4);
        v4f aNi = mfma16(g00, B[2][0], biasNi4);
        aR0 = mfma16(g01, B[0][1], aR0);
        aZ0 = mfma16(g01, B[1][1], aZ0);
        aNi = mfma16(g01, B[2][1], aNi);
        __builtin_amdgcn_s_setprio(0);
        const v4f aR = aR1 + aR0;
        const v4f aZ = aZ1 + aZ0;

        const v2f h01 = gru_cell2((v2f){aR[0], aR[1]},
                                  (v2f){aZ[0], aZ[1]},
                                  (v2f){aNi[0], aNi[1]},
                                  (v2f){aNh[0], aNh[1]}, hA);
        const v2f h23 = gru_cell2((v2f){aR[2], aR[3]},
                                  (v2f){aZ[2], aZ[3]},
                                  (v2f){aNi[2], aNi[3]},
                                  (v2f){aNh[2], aNh[3]}, hB);
        hA = h01; hB = h23;
        _Float16* wp = &h1f[pw][(4 * q) * KS + u];
        wp[0]      = (_Float16)h01.x;
        wp[KS]     = (_Float16)h01.y;
        wp[2 * KS] = (_Float16)h23.x;
        wp[3 * KS] = (_Float16)h23.y;
    };

    // ---- window schedule: k=0 (grp0 only), pairs (odd,even), k=T_LEN-1,
    // then k=T_LEN (grp1 only). 513 windows total, parity literal each.
    if (grp == 0) grp0_step(0, 0);
    __syncthreads();
    #pragma unroll 1
    for (int kk = 1; kk + 1 < T_LEN; kk += 2) {
        if (grp == 0) grp0_step(kk, 1); else grp1_step(1);
        __syncthreads();
        if (grp == 0) grp0_step(kk + 1, 0); else grp1_step(0);
        __syncthreads();
    }
    if (grp == 0) grp0_step(T_LEN - 1, 1); else grp1_step(1);
    __syncthreads();
    if (grp == 1) grp1_step(0);              // window k = T_LEN, t = T_LEN-1
    __syncthreads();

    // ======== FC epilogue: out[m] = sum_u fc_w[u] h1[m][u] + fc_b ========
    if (grp == 1) {
        const float fw = fc_w[u];
        const float hv[4] = {hA.x, hA.y, hB.x, hB.y};
        #pragma unroll
        for (int r = 0; r < 4; r++) {
            float v = fw * hv[r];
            v += __shfl_xor(v, 1, 64);
            v += __shfl_xor(v, 2, 64);
            v += __shfl_xor(v, 4, 64);
            v += __shfl_xor(v, 8, 64);   // sum over 16 n-lanes (q preserved)
            if (n == 0) red[(4 * q + r) * 4 + w] = v;
        }
    }
    __syncthreads();
    if (tid < 16) {
        const float s = red[tid * 4] + red[tid * 4 + 1] + red[tid * 4 + 2] + red[tid * 4 + 3];
        out[blockIdx.x * 16 + tid] = s + fc_b[0];
    }
}

extern "C" void kernel_launch(void* const* d_in, const int* in_sizes, int n_in,
                              void* d_out, int out_size, void* d_ws, size_t ws_size,
                              hipStream_t stream)
{
    const float* x     = (const float*)d_in[0];
    const float* w_ih0 = (const float*)d_in[1];
    const float* w_hh0 = (const float*)d_in[2];
    const float* b_ih0 = (const float*)d_in[3];
    const float* b_hh0 = (const float*)d_in[4];
    const float* w_ih1 = (const float*)d_in[5];
    const float* w_hh1 = (const float*)d_in[6];
    const float* b_ih1 = (const float*)d_in[7];
    const float* b_hh1 = (const float*)d_in[8];
    const float* fc_w  = (const float*)d_in[9];
    const float* fc_b  = (const float*)d_in[10];
    float* out = (float*)d_out;

    hipLaunchKernelGGL(gru_mfma, dim3(256), dim3(512), 0, stream,
                       x, w_ih0, w_hh0, b_ih0, b_hh0,
                       w_ih1, w_hh1, b_ih1, b_hh1, fc_w, fc_b, out);
}

// Round 8
// 313.851 us; speedup vs baseline: 1.0659x; 1.0242x over previous
//
#include <hip/hip_runtime.h>

// GRUModel: 2-layer GRU (H=64), B=4096, T=512, fp32 in/out — MFMA round 19.
//
// Structural-floor analysis (R16-R18 measured): window 1353 cyc = 660 VALU +
// 360 MFMA + ~330 chain; the two co-resident waves (grp0,grp1) are
// phase-locked by the per-window barrier so VALU/MFMA phases are ADDITIVE.
// Phase diversity is closed: 8-row blocks double per-row issue (wave64
// issues regardless of exec mask); 32-row blocks idle half the CUs; counter
// barriers (R17) lose to spin issue on rate-matched streams. Trans (5/cell)
// and MFMA counts are exact-math minimal. R19 harvests intra-wave ILP only:
//   - gru_cell4: both cell-pairs fused, stage-interleaved; all 8 independent
//     exps (C and A of both pairs) issue BEFORE the serial rcp->fma->exp
//     tail, so pair-B trans latency hides under pair-A.
//   - xw prefetch: xh32 is static; read window k+1's x-word during window
//     k's cell phase (off the post-barrier chain).
//   - R18 tree-split kept (measured-neutral).
//
// Structure: 256 blocks x 512 threads; waves 0-3 layer 0 @ window k,
// waves 4-7 layer 1 @ k-1; fp16 MFMA operands; one barrier/window; parity
// double-buffered h planes; h-state fp32 in registers; x folded into MFMA;
// negated log2-domain gates; packed-f32 cell math.
//
// Frag layouts (m89/m120-verified):
//   A: lane holds A[m=lane&15][k=(lane>>4)*8+j], j=0..7
//   B: lane holds B[k=(lane>>4)*8+j][n=lane&15]
//   C/D: lane holds D[m=(lane>>4)*4+reg][n=lane&15]

typedef _Float16 half8 __attribute__((ext_vector_type(8)));
typedef float    v4f   __attribute__((ext_vector_type(4)));
typedef float    v2f   __attribute__((ext_vector_type(2)));
typedef unsigned uint4v __attribute__((ext_vector_type(4)));

#define T_LEN 512
#define KS 72   // fp16 row stride of h planes (16B-aligned b128 reads)

#define L2E  1.4426950408889634f   // log2(e)
#define L2E2 2.8853900817779268f   // 2*log2(e)

static __device__ __forceinline__ v4f mfma16(half8 a, half8 b, v4f c) {
    return __builtin_amdgcn_mfma_f32_16x16x32_f16(a, b, c, 0, 0, 0);
}
static __device__ __forceinline__ half8 ld8(const _Float16* p) {
    return *(const half8*)p;
}
static __device__ __forceinline__ v2f exp2v(v2f x) {
    v2f r; r.x = __builtin_amdgcn_exp2f(x.x); r.y = __builtin_amdgcn_exp2f(x.y);
    return r;
}
static __device__ __forceinline__ v2f rcpv(v2f x) {
    v2f r; r.x = __builtin_amdgcn_rcpf(x.x); r.y = __builtin_amdgcn_rcpf(x.y);
    return r;
}
// merged GRU cell x4 (two v2f pairs, stage-interleaved). Inputs PRE-NEGATED
// & log2-scaled: ar2=-log2e*(i_r+h_r), az2=-log2e*(i_z+h_z),
// ni2=-2log2e*i_n, nh2=-2log2e*h_n.
//   h' = [A(1-B) + h(1+B)] / [(1+A)(1+B)]; A=2^az2, B=2^wn, wn=ni2+r*nh2
// All 8 independent exps (C,A of both pairs) issue before the serial
// rcp->fma->exp tail so pair-B latency hides under pair-A.
static __device__ __forceinline__ void gru_cell4(
        v2f arA, v2f arB, v2f azA, v2f azB,
        v2f niA, v2f niB, v2f nhA, v2f nhB,
        v2f hA,  v2f hB,  v2f* oA, v2f* oB) {
    // stage 1: all independent exps
    const v2f CA = exp2v(arA);
    const v2f CB = exp2v(arB);
    const v2f AA = exp2v(azA);
    const v2f AB = exp2v(azB);
    // stage 2: sigmoids
    const v2f rA = rcpv(CA + 1.0f);
    const v2f rB = rcpv(CB + 1.0f);
    // stage 3: n-gate exponents
    const v2f wnA = __builtin_elementwise_fma(rA, nhA, niA);
    const v2f wnB = __builtin_elementwise_fma(rB, nhB, niB);
    // stage 4: n-gate exps
    const v2f BvA = exp2v(wnA);
    const v2f BvB = exp2v(wnB);
    // stage 5: combine
    const v2f aBA = BvA + 1.0f;
    const v2f aBB = BvB + 1.0f;
    const v2f numA = __builtin_elementwise_fma(hA, aBA, AA * (1.0f - BvA));
    const v2f numB = __builtin_elementwise_fma(hB, aBB, AB * (1.0f - BvB));
    const v2f denA = (AA + 1.0f) * aBA;
    const v2f denB = (AB + 1.0f) * aBB;
    *oA = numA * rcpv(denA);
    *oB = numB * rcpv(denB);
}

__global__ __launch_bounds__(512, 1)
void gru_mfma(const float* __restrict__ x,
              const float* __restrict__ w_ih0, const float* __restrict__ w_hh0,
              const float* __restrict__ b_ih0, const float* __restrict__ b_hh0,
              const float* __restrict__ w_ih1, const float* __restrict__ w_hh1,
              const float* __restrict__ b_ih1, const float* __restrict__ b_hh1,
              const float* __restrict__ fc_w,  const float* __restrict__ fc_b,
              float* __restrict__ out)
{
    // xh32[t][m]: fp16(x) in low 16 bits, high 16 = 0 — so a single
    // ds_read_b32 IS word0 of the x A-frag (elem0 = x, elem1 = 0).
    __shared__ __align__(16) unsigned xh32[T_LEN * 16];   // 32 KB
    __shared__ __align__(16) _Float16 h0f[2][16 * KS];    // h0 fp16, 2 parities
    __shared__ __align__(16) _Float16 h1f[2][16 * KS];    // h1 fp16, 2 parities
    __shared__ float red[64];

    const int tid  = threadIdx.x;
    const int wv   = tid >> 6;
    const int grp  = wv >> 2;       // 0 = layer-0 group, 1 = layer-1 group
    const int w    = wv & 3;        // N-split within group
    const int lane = tid & 63;
    const int n    = lane & 15;
    const int q    = lane >> 4;
    const int u    = w * 16 + n;    // unit owned in gate phase

    // ---- stage this block's 16 x-rows into LDS as fp16-packed [t][m] ----
    const float* xg = x + (size_t)(blockIdx.x * 16) * T_LEN;
    for (int i = tid; i < 16 * T_LEN; i += 512) {
        const int row = i >> 9, t = i & 511;
        const float v = xg[row * T_LEN + t];
        xh32[t * 16 + row] =
            (unsigned)__builtin_bit_cast(unsigned short, (_Float16)v);
    }
    // zero parity-1 buffers (read before first write)
    for (int i = tid; i < 16 * KS; i += 512) {
        h0f[1][i] = (_Float16)0;
        h1f[1][i] = (_Float16)0;
    }

    // ---- loop-invariant weight B-fragments, pre-scaled into NEGATED log2
    // domain. grp0 uses c=0,1 (W_hh0, K=64); grp1 uses c=0..3
    // ([W_ih1 | W_hh1], K=128). gates r,z scaled by -log2e; n by -2log2e.
    half8 B[3][4];
    {
        const int rows[3] = {u, 64 + u, 128 + u};
        const float sc[3] = {-L2E, -L2E, -L2E2};
        const float* bc[4];
        if (grp == 0) {
            bc[0] = w_hh0;      bc[1] = w_hh0 + 32;
            bc[2] = w_hh0;      bc[3] = w_hh0 + 32;   // unused dups
        } else {
            bc[0] = w_ih1;      bc[1] = w_ih1 + 32;
            bc[2] = w_hh1;      bc[3] = w_hh1 + 32;
        }
        #pragma unroll
        for (int g = 0; g < 3; g++)
            #pragma unroll
            for (int c = 0; c < 4; c++) {
                const float* r0 = bc[c] + rows[g] * 64 + 8 * q;
                #pragma unroll
                for (int j = 0; j < 8; j++) B[g][c][j] = (_Float16)(r0[j] * sc[g]);
            }
    }

    // ---- x-chunk B-frags (grp0 only): Bx row k=0 = scaled w_ih0 gate row,
    // rows 1..31 = 0  ->  lane (q==0, j==0) holds w, all else 0.
    half8 BX[3];
    {
        const float sc3[3] = {-L2E, -L2E, -L2E2};
        #pragma unroll
        for (int g = 0; g < 3; g++) {
            uint4v z = {0u, 0u, 0u, 0u};
            if (grp == 0 && q == 0) {
                const _Float16 wv16 = (_Float16)(w_ih0[g * 64 + u] * sc3[g]);
                z.x = (unsigned)__builtin_bit_cast(unsigned short, wv16);
            }
            BX[g] = __builtin_bit_cast(half8, z);
        }
    }

    // per-lane gate bias constants for unit u (group-specific), -log2 scaled
    float brc, bzc, binc, bhnc;
    if (grp == 0) {
        brc = -(b_ih0[u] + b_hh0[u]) * L2E;
        bzc = -(b_ih0[64 + u] + b_hh0[64 + u]) * L2E;
        binc = -b_ih0[128 + u] * L2E2; bhnc = -b_hh0[128 + u] * L2E2;
    } else {
        brc = -(b_ih1[u] + b_hh1[u]) * L2E;
        bzc = -(b_ih1[64 + u] + b_hh1[64 + u]) * L2E;
        binc = -b_ih1[128 + u] * L2E2; bhnc = -b_hh1[128 + u] * L2E2;
    }

    // loop-invariant bias splats: C operand of the FIRST MFMA of each chain.
    const v4f biasR4  = {brc,  brc,  brc,  brc};
    const v4f biasZ4  = {bzc,  bzc,  bzc,  bzc};
    const v4f biasNi4 = {binc, binc, binc, binc};
    const v4f biasNh4 = {bhnc, bhnc, bhnc, bhnc};
    const v4f zero4   = {0.f, 0.f, 0.f, 0.f};

    v2f hA = {0.f, 0.f}, hB = {0.f, 0.f};   // fp32 h[m=4q+{0,1,2,3}][u]

    __syncthreads();

    const int abase = n * KS + 8 * q;       // A-frag base (fp16 elems)

    // xw prefetch register (grp0): x-word for the CURRENT window, loaded
    // one window ahead (xh32 is static after staging).
    unsigned xwcur = (grp == 0) ? xh32[n] : 0u;   // window k=0

    // ---- window bodies; P = window parity, a LITERAL at every call site
    // so all parity-dependent LDS addresses fold to constants.
    auto grp0_step = [&](int k, int P) __attribute__((always_inline)) {
        const int pw = P, pr = P ^ 1;
        // A-frags of h0(k-1) — written @k-1 pre-barrier, visible now
        const half8 a0 = ld8(&h0f[pr][abase]);
        const half8 a1 = ld8(&h0f[pr][abase + 32]);
        // x A-frag: k-slot 0 = x[m=n][t=k] (only q==0 lanes non-zero)
        uint4v ax32 = {0u, 0u, 0u, 0u};
        ax32.x = (q == 0) ? xwcur : 0u;
        const half8 ax = __builtin_bit_cast(half8, ax32);

        __builtin_amdgcn_s_setprio(1);
        v4f accR = mfma16(ax, BX[0], biasR4);
        v4f accZ = mfma16(ax, BX[1], biasZ4);
        v4f aNi  = mfma16(ax, BX[2], biasNi4);
        v4f accN = mfma16(a0, B[2][0], biasNh4);
        accR = mfma16(a0, B[0][0], accR);
        accZ = mfma16(a0, B[1][0], accZ);
        accN = mfma16(a1, B[2][1], accN);
        accR = mfma16(a1, B[0][1], accR);
        accZ = mfma16(a1, B[1][1], accZ);
        __builtin_amdgcn_s_setprio(0);

        // prefetch next window's x-word (static LDS, off the barrier chain)
        xwcur = xh32[((k + 1) & (T_LEN - 1)) * 16 + n];

        v2f h01, h23;
        gru_cell4((v2f){accR[0], accR[1]}, (v2f){accR[2], accR[3]},
                  (v2f){accZ[0], accZ[1]}, (v2f){accZ[2], accZ[3]},
                  (v2f){aNi[0],  aNi[1]},  (v2f){aNi[2],  aNi[3]},
                  (v2f){accN[0], accN[1]}, (v2f){accN[2], accN[3]},
                  hA, hB, &h01, &h23);
        hA = h01; hB = h23;
        _Float16* wp = &h0f[pw][(4 * q) * KS + u];
        wp[0]      = (_Float16)h01.x;
        wp[KS]     = (_Float16)h01.y;
        wp[2 * KS] = (_Float16)h23.x;
        wp[3 * KS] = (_Float16)h23.y;
    };

    auto grp1_step = [&](int P) __attribute__((always_inline)) {
        // window k has parity P; consumes h0(t=k-1) (parity P^1) and
        // h1(t-1) (parity P), writes h1(t) at parity P^1.
        const int pw = P ^ 1, p1 = P;
        // own-layer frags first: written a full window ago, reads ready
        const half8 g10 = ld8(&h1f[p1][abase]);        // h1(t-1)
        const half8 g11 = ld8(&h1f[p1][abase + 32]);
        const half8 g00 = ld8(&h0f[pw][abase]);        // h0new(t)
        const half8 g01 = ld8(&h0f[pw][abase + 32]);

        __builtin_amdgcn_s_setprio(1);
        // TREE-SPLIT (R18): aR/aZ as two independent depth-2 chains + add.
        v4f aR1 = mfma16(g10, B[0][2], biasR4);
        v4f aZ1 = mfma16(g10, B[1][2], biasZ4);
        v4f aNh = mfma16(g10, B[2][2], biasNh4);
        aR1 = mfma16(g11, B[0][3], aR1);
        aZ1 = mfma16(g11, B[1][3], aZ1);
        aNh = mfma16(g11, B[2][3], aNh);
        v4f aR0 = mfma16(g00, B[0][0], zero4);
        v4f aZ0 = mfma16(g00, B[1][0], zero4);
        v4f aNi = mfma16(g00, B[2][0], biasNi4);
        aR0 = mfma16(g01, B[0][1], aR0);
        aZ0 = mfma16(g01, B[1][1], aZ0);
        aNi = mfma16(g01, B[2][1], aNi);
        __builtin_amdgcn_s_setprio(0);
        const v4f aR = aR1 + aR0;
        const v4f aZ = aZ1 + aZ0;

        v2f h01, h23;
        gru_cell4((v2f){aR[0], aR[1]},  (v2f){aR[2], aR[3]},
                  (v2f){aZ[0], aZ[1]},  (v2f){aZ[2], aZ[3]},
                  (v2f){aNi[0], aNi[1]}, (v2f){aNi[2], aNi[3]},
                  (v2f){aNh[0], aNh[1]}, (v2f){aNh[2], aNh[3]},
                  hA, hB, &h01, &h23);
        hA = h01; hB = h23;
        _Float16* wp = &h1f[pw][(4 * q) * KS + u];
        wp[0]      = (_Float16)h01.x;
        wp[KS]     = (_Float16)h01.y;
        wp[2 * KS] = (_Float16)h23.x;
        wp[3 * KS] = (_Float16)h23.y;
    };

    // ---- window schedule: k=0 (grp0 only), pairs (odd,even), k=T_LEN-1,
    // then k=T_LEN (grp1 only). 513 windows total, parity literal each.
    if (grp == 0) grp0_step(0, 0);
    __syncthreads();
    #pragma unroll 1
    for (int kk = 1; kk + 1 < T_LEN; kk += 2) {
        if (grp == 0) grp0_step(kk, 1); else grp1_step(1);
        __syncthreads();
        if (grp == 0) grp0_step(kk + 1, 0); else grp1_step(0);
        __syncthreads();
    }
    if (grp == 0) grp0_step(T_LEN - 1, 1); else grp1_step(1);
    __syncthreads();
    if (grp == 1) grp1_step(0);              // window k = T_LEN, t = T_LEN-1
    __syncthreads();

    // ======== FC epilogue: out[m] = sum_u fc_w[u] h1[m][u] + fc_b ========
    if (grp == 1) {
        const float fw = fc_w[u];
        const float hv[4] = {hA.x, hA.y, hB.x, hB.y};
        #pragma unroll
        for (int r = 0; r < 4; r++) {
            float v = fw * hv[r];
            v += __shfl_xor(v, 1, 64);
            v += __shfl_xor(v, 2, 64);
            v += __shfl_xor(v, 4, 64);
            v += __shfl_xor(v, 8, 64);   // sum over 16 n-lanes (q preserved)
            if (n == 0) red[(4 * q + r) * 4 + w] = v;
        }
    }
    __syncthreads();
    if (tid < 16) {
        const float s = red[tid * 4] + red[tid * 4 + 1] + red[tid * 4 + 2] + red[tid * 4 + 3];
        out[blockIdx.x * 16 + tid] = s + fc_b[0];
    }
}

extern "C" void kernel_launch(void* const* d_in, const int* in_sizes, int n_in,
                              void* d_out, int out_size, void* d_ws, size_t ws_size,
                              hipStream_t stream)
{
    const float* x     = (const float*)d_in[0];
    const float* w_ih0 = (const float*)d_in[1];
    const float* w_hh0 = (const float*)d_in[2];
    const float* b_ih0 = (const float*)d_in[3];
    const float* b_hh0 = (const float*)d_in[4];
    const float* w_ih1 = (const float*)d_in[5];
    const float* w_hh1 = (const float*)d_in[6];
    const float* b_ih1 = (const float*)d_in[7];
    const float* b_hh1 = (const float*)d_in[8];
    const float* fc_w  = (const float*)d_in[9];
    const float* fc_b  = (const float*)d_in[10];
    float* out = (float*)d_out;

    hipLaunchKernelGGL(gru_mfma, dim3(256), dim3(512), 0, stream,
                       x, w_ih0, w_hh0, b_ih0, b_hh0,
                       w_ih1, w_hh1, b_ih1, b_hh1, fc_w, fc_b, out);
}